// Round 1
// baseline (899.306 us; speedup 1.0000x reference)
//
#include <hip/hip_runtime.h>

// GCN: h1 = relu( Din^-1/2 * A * Dout^-1/2 * (X W1) + b1 )
//      h2 =       Din^-1/2 * A * Dout^-1/2 * (h1 W2) + b2
//      out = mean_nodes(h2)                         [128]
// N=50000 nodes, E=800000 edges, F: 256 -> 256 -> 128, all fp32.

#define NNODES 50000
#define NEDGES 800000

// ---------------- degree count ----------------
__global__ void k_degrees(const int* __restrict__ src, const int* __restrict__ dst,
                          int* __restrict__ degOut, int* __restrict__ degIn, int ne) {
    int e = blockIdx.x * blockDim.x + threadIdx.x;
    if (e < ne) {
        atomicAdd(&degOut[src[e]], 1);
        atomicAdd(&degIn[dst[e]], 1);
    }
}

// ---------------- norms ----------------
__global__ void k_norms(const int* __restrict__ degOut, const int* __restrict__ degIn,
                        float* __restrict__ normOut, float* __restrict__ normIn, int n) {
    int i = blockIdx.x * blockDim.x + threadIdx.x;
    if (i < n) {
        normOut[i] = rsqrtf((float)max(degOut[i], 1));
        normIn[i]  = rsqrtf((float)max(degIn[i], 1));
    }
}

// ---------------- exclusive scan of degIn -> rowPtr (+ fill copy) ----------------
// single block, 1024 threads, 49 elems/thread (1024*49 = 50176 >= 50000)
__global__ __launch_bounds__(1024) void k_scan(const int* __restrict__ degIn,
                                               int* __restrict__ rowPtr,
                                               int* __restrict__ fill, int n) {
    const int CH = 49;
    __shared__ int ssum[1024];
    int t = threadIdx.x;
    int lo = t * CH;
    int hi = min(lo + CH, n);
    int s = 0;
    for (int i = lo; i < hi; i++) s += degIn[i];
    ssum[t] = s;
    __syncthreads();
    for (int off = 1; off < 1024; off <<= 1) {
        int v = (t >= off) ? ssum[t - off] : 0;
        __syncthreads();
        ssum[t] += v;
        __syncthreads();
    }
    int run = ssum[t] - s;  // exclusive prefix
    for (int i = lo; i < hi; i++) {
        rowPtr[i] = run;
        fill[i] = run;
        run += degIn[i];
    }
    if (t == blockDim.x - 1) rowPtr[n] = ssum[t];
}

// ---------------- scatter edges into CSR buckets (row = dst, col = src) ----------------
__global__ void k_scatter(const int* __restrict__ src, const int* __restrict__ dst,
                          int* __restrict__ fill, int* __restrict__ col, int ne) {
    int e = blockIdx.x * blockDim.x + threadIdx.x;
    if (e < ne) {
        int p = atomicAdd(&fill[dst[e]], 1);
        col[p] = src[e];
    }
}

// ---------------- fp32 GEMM: H[m][n] = (sum_k X[m][k] W[k][n]) * normOut[m] ----------------
// BM=64, BN=64, BK=16, 256 threads, 4x4 micro-tile per thread.
__global__ __launch_bounds__(256) void k_gemm_norm(
    const float* __restrict__ X, const float* __restrict__ W,
    const float* __restrict__ normOut, float* __restrict__ H,
    int M, int N, int K) {
    __shared__ float As[64][20];  // pad 20: 16B-aligned float4 writes, 2-way-max read conflicts
    __shared__ float Bs[16][68];  // pad 68: spread staging writes across banks

    int tid = threadIdx.x;
    int bm = blockIdx.x, bn = blockIdx.y;
    int tx = tid & 15, ty = tid >> 4;

    float acc[4][4] = {};

    int xr = bm * 64 + (tid >> 2);
    int xrc = min(xr, M - 1);         // clamp: stores are guarded
    int xc0 = (tid & 3) * 4;
    int wr = tid >> 4;                // 0..15
    int wc = (tid & 15) * 4;          // 0..60
    const float* Wb = W + bn * 64;

    for (int k0 = 0; k0 < K; k0 += 16) {
        float4 av = *(const float4*)(X + (size_t)xrc * K + k0 + xc0);
        float4 bv = *(const float4*)(Wb + (size_t)(k0 + wr) * N + wc);
        *(float4*)&As[tid >> 2][xc0] = av;
        *(float4*)&Bs[wr][wc] = bv;
        __syncthreads();
#pragma unroll
        for (int k = 0; k < 16; k++) {
            float a0 = As[ty * 4 + 0][k];
            float a1 = As[ty * 4 + 1][k];
            float a2 = As[ty * 4 + 2][k];
            float a3 = As[ty * 4 + 3][k];
            float4 b = *(const float4*)&Bs[k][tx * 4];
            acc[0][0] += a0 * b.x; acc[0][1] += a0 * b.y; acc[0][2] += a0 * b.z; acc[0][3] += a0 * b.w;
            acc[1][0] += a1 * b.x; acc[1][1] += a1 * b.y; acc[1][2] += a1 * b.z; acc[1][3] += a1 * b.w;
            acc[2][0] += a2 * b.x; acc[2][1] += a2 * b.y; acc[2][2] += a2 * b.z; acc[2][3] += a2 * b.w;
            acc[3][0] += a3 * b.x; acc[3][1] += a3 * b.y; acc[3][2] += a3 * b.z; acc[3][3] += a3 * b.w;
        }
        __syncthreads();
    }

#pragma unroll
    for (int i = 0; i < 4; i++) {
        int m = bm * 64 + ty * 4 + i;
        if (m < M) {
            float nm = normOut[m];
            float4 o;
            o.x = acc[i][0] * nm; o.y = acc[i][1] * nm;
            o.z = acc[i][2] * nm; o.w = acc[i][3] * nm;
            *(float4*)(H + (size_t)m * N + bn * 64 + tx * 4) = o;
        }
    }
}

// ---------------- SpMM layer1: O[n] = relu(normIn[n] * sum_{e in row n} H[col[e]] + b), F=256 ----------------
// one wave per node, 4 nodes per 256-thread block, float4 per lane (64*4 = 256 feats)
__global__ __launch_bounds__(256) void k_spmm_relu(
    const float* __restrict__ H, const int* __restrict__ rowPtr, const int* __restrict__ col,
    const float* __restrict__ normIn, const float* __restrict__ bias,
    float* __restrict__ O, int n) {
    int wave = threadIdx.x >> 6;
    int lane = threadIdx.x & 63;
    int node = blockIdx.x * 4 + wave;
    if (node >= n) return;
    int s = rowPtr[node], e = rowPtr[node + 1];
    int f = lane * 4;
    float4 acc = make_float4(0.f, 0.f, 0.f, 0.f);
    for (int i = s; i < e; i++) {
        int c = __builtin_amdgcn_readfirstlane(col[i]);  // wave-uniform
        const float4 v = *(const float4*)(H + (size_t)c * 256 + f);
        acc.x += v.x; acc.y += v.y; acc.z += v.z; acc.w += v.w;
    }
    float nm = normIn[node];
    float4 b = *(const float4*)(bias + f);
    float4 o;
    o.x = fmaxf(acc.x * nm + b.x, 0.f);
    o.y = fmaxf(acc.y * nm + b.y, 0.f);
    o.z = fmaxf(acc.z * nm + b.z, 0.f);
    o.w = fmaxf(acc.w * nm + b.w, 0.f);
    *(float4*)(O + (size_t)node * 256 + f) = o;
}

// ---------------- SpMM layer2 + fused mean pool, F=128 ----------------
// one wave per node (float2/lane), block reduces its 4 nodes in LDS, one atomicAdd/feature/block.
__global__ __launch_bounds__(256) void k_spmm_mean(
    const float* __restrict__ H, const int* __restrict__ rowPtr, const int* __restrict__ col,
    const float* __restrict__ normIn, const float* __restrict__ bias,
    float* __restrict__ out, int n) {
    __shared__ float sm[4][128];
    int wave = threadIdx.x >> 6;
    int lane = threadIdx.x & 63;
    int node = blockIdx.x * 4 + wave;
    int f = lane * 2;
    float ax = 0.f, ay = 0.f;
    if (node < n) {
        int s = rowPtr[node], e = rowPtr[node + 1];
        for (int i = s; i < e; i++) {
            int c = __builtin_amdgcn_readfirstlane(col[i]);
            const float2 v = *(const float2*)(H + (size_t)c * 128 + f);
            ax += v.x; ay += v.y;
        }
        const float inv = 1.0f / (float)NNODES;
        float nm = normIn[node];
        ax = (ax * nm + bias[f])     * inv;
        ay = (ay * nm + bias[f + 1]) * inv;
    }
    sm[wave][f] = ax;
    sm[wave][f + 1] = ay;
    __syncthreads();
    if (threadIdx.x < 128) {
        float s4 = sm[0][threadIdx.x] + sm[1][threadIdx.x] + sm[2][threadIdx.x] + sm[3][threadIdx.x];
        atomicAdd(&out[threadIdx.x], s4);
    }
}

extern "C" void kernel_launch(void* const* d_in, const int* in_sizes, int n_in,
                              void* d_out, int out_size, void* d_ws, size_t ws_size,
                              hipStream_t stream) {
    const float* X   = (const float*)d_in[0];  // [50000,256]
    const int*   src = (const int*)d_in[1];    // [800000]
    const int*   dst = (const int*)d_in[2];    // [800000]
    const float* W1  = (const float*)d_in[3];  // [256,256]
    const float* b1  = (const float*)d_in[4];  // [256]
    const float* W2  = (const float*)d_in[5];  // [256,128]
    const float* b2  = (const float*)d_in[6];  // [128]
    float* out = (float*)d_out;                // [128]

    const int n  = NNODES;
    const int ne = NEDGES;

    // ---- workspace carve (256B aligned) ----
    char* p = (char*)d_ws;
    auto carve = [&](size_t bytes) -> void* {
        void* r = (void*)p;
        p += (bytes + 255) & ~(size_t)255;
        return r;
    };
    int*   degOut  = (int*)carve((size_t)2 * n * sizeof(int));  // degOut + degIn adjacent
    int*   degIn   = degOut + n;
    float* normOut = (float*)carve((size_t)n * sizeof(float));
    float* normIn  = (float*)carve((size_t)n * sizeof(float));
    int*   rowPtr  = (int*)carve((size_t)(n + 1) * sizeof(int));
    int*   fill    = (int*)carve((size_t)n * sizeof(int));
    int*   col     = (int*)carve((size_t)ne * sizeof(int));
    float* bufA    = (float*)carve((size_t)n * 256 * sizeof(float));  // h (pre-agg), reused as h2
    float* bufB    = (float*)carve((size_t)n * 256 * sizeof(float));  // relu'd h1

    // ---- init (capturable async memsets) ----
    hipMemsetAsync(degOut, 0, (size_t)2 * n * sizeof(int), stream);
    hipMemsetAsync(out, 0, 128 * sizeof(float), stream);

    // ---- graph structure (shared by both layers) ----
    k_degrees<<<(ne + 255) / 256, 256, 0, stream>>>(src, dst, degOut, degIn, ne);
    k_norms<<<(n + 255) / 256, 256, 0, stream>>>(degOut, degIn, normOut, normIn, n);
    k_scan<<<1, 1024, 0, stream>>>(degIn, rowPtr, fill, n);
    k_scatter<<<(ne + 255) / 256, 256, 0, stream>>>(src, dst, fill, col, ne);

    // ---- layer 1 ----
    dim3 g1((n + 63) / 64, 256 / 64);
    k_gemm_norm<<<g1, 256, 0, stream>>>(X, W1, normOut, bufA, n, 256, 256);
    k_spmm_relu<<<(n + 3) / 4, 256, 0, stream>>>(bufA, rowPtr, col, normIn, b1, bufB, n);

    // ---- layer 2 (+ fused mean) ----
    dim3 g2((n + 63) / 64, 128 / 64);
    k_gemm_norm<<<g2, 256, 0, stream>>>(bufB, W2, normOut, bufA, n, 128, 256);
    k_spmm_mean<<<(n + 3) / 4, 256, 0, stream>>>(bufA, rowPtr, col, normIn, b2, out, n);
}